// Round 1
// baseline (597.400 us; speedup 1.0000x reference)
//
#include <hip/hip_runtime.h>

// ---------- types / helpers ----------
using s16x8 = __attribute__((ext_vector_type(8))) short;   // 8 x bf16 bits
using s16x4 = __attribute__((ext_vector_type(4))) short;
using f32x4 = __attribute__((ext_vector_type(4))) float;

#define LOG2E 1.4426950408889634f

static __device__ __forceinline__ ushort f2bf(float f) {
    union { float f; unsigned u; } c; c.f = f;
    unsigned u = c.u;
    unsigned r = (u + 0x7fffu + ((u >> 16) & 1u)) >> 16;   // RNE
    return (ushort)r;
}
static __device__ __forceinline__ float bf2f(ushort h) {
    union { unsigned u; float f; } c; c.u = ((unsigned)h) << 16;
    return c.f;
}

// ---------- weight prep: W[k][n] f32 -> Wt[n][k] bf16 (tiled transpose) ----------
__global__ __launch_bounds__(256) void wprep_kernel(const float* __restrict__ W,
                                                    ushort* __restrict__ Wt) {
    __shared__ float tile[32][33];
    const int k0 = blockIdx.x * 32, n0 = blockIdx.y * 32;
    const int tx = threadIdx.x & 31, ty = threadIdx.x >> 5;   // 32 x 8
    #pragma unroll
    for (int i = 0; i < 32; i += 8)
        tile[ty + i][tx] = W[(size_t)(k0 + ty + i) * 1024 + n0 + tx];
    __syncthreads();
    #pragma unroll
    for (int i = 0; i < 32; i += 8)
        Wt[(size_t)(n0 + ty + i) * 1024 + k0 + tx] = f2bf(tile[tx][ty + i]);
}

// ---------- LayerNorm: x[8192][1024] f32 -> xn bf16 ----------
__global__ __launch_bounds__(256) void ln_kernel(const float* __restrict__ x,
                                                 const float* __restrict__ w,
                                                 const float* __restrict__ b,
                                                 ushort* __restrict__ xn) {
    const int row = blockIdx.x;
    const float4 v = ((const float4*)(x + (size_t)row * 1024))[threadIdx.x];
    float s  = v.x + v.y + v.z + v.w;
    float s2 = v.x * v.x + v.y * v.y + v.z * v.z + v.w * v.w;
    #pragma unroll
    for (int off = 1; off < 64; off <<= 1) {
        s  += __shfl_xor(s, off);
        s2 += __shfl_xor(s2, off);
    }
    __shared__ float red[8];
    const int wid = threadIdx.x >> 6, lane = threadIdx.x & 63;
    if (lane == 0) { red[wid] = s; red[4 + wid] = s2; }
    __syncthreads();
    s  = red[0] + red[1] + red[2] + red[3];
    s2 = red[4] + red[5] + red[6] + red[7];
    const float mu = s * (1.0f / 1024.0f);
    const float var = s2 * (1.0f / 1024.0f) - mu * mu;
    const float rstd = rsqrtf(var + 1e-5f);
    const float4 wv = ((const float4*)w)[threadIdx.x];
    const float4 bv = ((const float4*)b)[threadIdx.x];
    s16x4 o;
    o[0] = (short)f2bf((v.x - mu) * rstd * wv.x + bv.x);
    o[1] = (short)f2bf((v.y - mu) * rstd * wv.y + bv.y);
    o[2] = (short)f2bf((v.z - mu) * rstd * wv.z + bv.z);
    o[3] = (short)f2bf((v.w - mu) * rstd * wv.w + bv.w);
    ((s16x4*)xn)[(size_t)row * 256 + threadIdx.x] = o;
}

// ---------- GEMM: C[8192,1024] = A[8192,1024] @ W  (Wt[n][k] bf16) ----------
// mode 0: write bf16 head-major [b,h,i,d]     (Q, K)
// mode 2: write bf16 head-transposed [b,h,d,i] (V)
// mode 3: write f32 plain [row][col]           (final output)
__global__ __launch_bounds__(256) void gemm_kernel(const ushort* __restrict__ A,
                                                   const ushort* __restrict__ Wt,
                                                   void* __restrict__ outp, int mode) {
    const int wid = threadIdx.x >> 6;
    const int lane = threadIdx.x & 63;
    const int l15 = lane & 15;
    const int lg  = lane >> 4;
    const int m0 = blockIdx.y * 128 + (wid >> 1) * 64;
    const int n0 = blockIdx.x * 128 + (wid & 1) * 64;

    f32x4 acc[4][4] = {};
    for (int k0 = 0; k0 < 1024; k0 += 32) {
        const int ka = k0 + lg * 8;
        s16x8 a[4], bfr[4];
        #pragma unroll
        for (int mi = 0; mi < 4; ++mi)
            a[mi] = *(const s16x8*)(A + (size_t)(m0 + mi * 16 + l15) * 1024 + ka);
        #pragma unroll
        for (int ni = 0; ni < 4; ++ni)
            bfr[ni] = *(const s16x8*)(Wt + (size_t)(n0 + ni * 16 + l15) * 1024 + ka);
        #pragma unroll
        for (int mi = 0; mi < 4; ++mi)
            #pragma unroll
            for (int ni = 0; ni < 4; ++ni)
                acc[mi][ni] = __builtin_amdgcn_mfma_f32_16x16x32_bf16(a[mi], bfr[ni], acc[mi][ni], 0, 0, 0);
    }

    #pragma unroll
    for (int mi = 0; mi < 4; ++mi) {
        #pragma unroll
        for (int ni = 0; ni < 4; ++ni) {
            const int row = m0 + mi * 16 + lg * 4;       // + r
            const int col = n0 + ni * 16 + l15;
            if (mode == 0) {
                const int bb = row >> 11, i = row & 2047;
                const int h = col >> 6, d = col & 63;
                ushort* o = (ushort*)outp;
                const size_t base = (((size_t)(bb * 16 + h)) * 2048 + i) * 64 + d;
                #pragma unroll
                for (int r = 0; r < 4; ++r) o[base + (size_t)r * 64] = f2bf(acc[mi][ni][r]);
            } else if (mode == 2) {
                const int bb = row >> 11, i = row & 2047;
                const int h = col >> 6, d = col & 63;
                ushort* o = (ushort*)outp;
                const size_t base = (((size_t)(bb * 16 + h)) * 64 + d) * 2048 + i;
                s16x4 pk;
                #pragma unroll
                for (int r = 0; r < 4; ++r) pk[r] = (short)f2bf(acc[mi][ni][r]);
                *(s16x4*)(o + base) = pk;
            } else {
                float* o = (float*)outp;
                #pragma unroll
                for (int r = 0; r < 4; ++r) o[(size_t)(row + r) * 1024 + col] = acc[mi][ni][r];
            }
        }
    }
}

// ---------- attention: per (b,h), flash over keys, ALiBi computed analytically ----------
// Q,K: [bh][2048][64] bf16 ; Vt: [bh][64][2048] bf16 ; O: [b][i][1024] bf16
__global__ __launch_bounds__(256) void attn_kernel(const ushort* __restrict__ Q,
                                                   const ushort* __restrict__ K,
                                                   const ushort* __restrict__ Vt,
                                                   ushort* __restrict__ O) {
    __shared__ ushort Kl[64 * 64];
    __shared__ ushort Vl[64 * 64];
    __shared__ ushort Pl[4][16 * 64];

    const int bh = blockIdx.y;
    const int b = bh >> 4, h = bh & 15;
    const int q0 = blockIdx.x * 64;
    const int wid = threadIdx.x >> 6, lane = threadIdx.x & 63;
    const int l15 = lane & 15, lg = lane >> 4;
    const float slope = exp2f(-8.0f / (float)(16 - h));

    const ushort* Qh = Q + (size_t)bh * 2048 * 64;
    const ushort* Kh = K + (size_t)bh * 2048 * 64;
    const ushort* Vh = Vt + (size_t)bh * 64 * 2048;

    // Q fragments: wave wid owns q rows [q0+wid*16, +16)
    const int qrow = q0 + wid * 16 + l15;
    s16x8 qf[2];
    qf[0] = *(const s16x8*)(Qh + (size_t)qrow * 64 + lg * 8);
    qf[1] = *(const s16x8*)(Qh + (size_t)qrow * 64 + 32 + lg * 8);

    float m_run[4], l_run[4];
    f32x4 oacc[4] = {};
    #pragma unroll
    for (int r = 0; r < 4; ++r) { m_run[r] = -1e30f; l_run[r] = 0.0f; }

    for (int j0 = 0; j0 < 2048; j0 += 64) {
        __syncthreads();   // previous iter's K/V reads done before overwrite
        {
            const int t = threadIdx.x;
            #pragma unroll
            for (int it = 0; it < 2; ++it) {
                const int idx = t + it * 256;            // 0..511
                const int row = idx >> 3, c8 = (idx & 7) * 8;
                int byte = row * 128 + c8 * 2;
                byte ^= (row & 7) << 4;                  // bank-conflict swizzle
                *(s16x8*)((char*)Kl + byte) = *(const s16x8*)(Kh + (size_t)(j0 + row) * 64 + c8);
                *(s16x8*)((char*)Vl + byte) = *(const s16x8*)(Vh + (size_t)row * 2048 + j0 + c8);
            }
        }
        __syncthreads();

        // S = Q K^T  (16 q-rows x 64 keys per wave)
        float s[4][4];                                    // [jj][r]
        #pragma unroll
        for (int jj = 0; jj < 4; ++jj) {
            f32x4 sacc = {};
            #pragma unroll
            for (int kk = 0; kk < 2; ++kk) {
                const int row = jj * 16 + l15;
                int byte = row * 128 + (kk * 32 + lg * 8) * 2;
                byte ^= (row & 7) << 4;
                const s16x8 kf = *(const s16x8*)((const char*)Kl + byte);
                sacc = __builtin_amdgcn_mfma_f32_16x16x32_bf16(qf[kk], kf, sacc, 0, 0, 0);
            }
            #pragma unroll
            for (int r = 0; r < 4; ++r) s[jj][r] = sacc[r];
        }

        // scale + ALiBi + online softmax
        #pragma unroll
        for (int r = 0; r < 4; ++r) {
            const int qi = q0 + wid * 16 + lg * 4 + r;
            float mx = m_run[r];
            #pragma unroll
            for (int jj = 0; jj < 4; ++jj) {
                const int kj = j0 + jj * 16 + l15;
                const float v = s[jj][r] * 0.125f - slope * fabsf((float)(qi - kj));
                s[jj][r] = v;
                mx = fmaxf(mx, v);
            }
            #pragma unroll
            for (int off = 1; off < 16; off <<= 1) mx = fmaxf(mx, __shfl_xor(mx, off));
            const float sc = exp2f((m_run[r] - mx) * LOG2E);
            l_run[r] *= sc;
            #pragma unroll
            for (int dt = 0; dt < 4; ++dt) oacc[dt][r] *= sc;
            m_run[r] = mx;
            float ps = 0.0f;
            #pragma unroll
            for (int jj = 0; jj < 4; ++jj) {
                const float p = exp2f((s[jj][r] - mx) * LOG2E);
                s[jj][r] = p;
                ps += p;
            }
            #pragma unroll
            for (int off = 1; off < 16; off <<= 1) ps += __shfl_xor(ps, off);
            l_run[r] += ps;
        }

        // P -> LDS (per-wave region), re-read in A-fragment layout
        #pragma unroll
        for (int jj = 0; jj < 4; ++jj)
            #pragma unroll
            for (int r = 0; r < 4; ++r) {
                const int row = lg * 4 + r;
                int byte = row * 128 + (jj * 16 + l15) * 2;
                byte ^= (row & 7) << 4;
                *(ushort*)((char*)&Pl[wid][0] + byte) = f2bf(s[jj][r]);
            }
        s16x8 pf[2];
        #pragma unroll
        for (int kk = 0; kk < 2; ++kk) {
            const int row = l15;
            int byte = row * 128 + (kk * 32 + lg * 8) * 2;
            byte ^= (row & 7) << 4;
            pf[kk] = *(const s16x8*)((const char*)&Pl[wid][0] + byte);
        }
        // O += P @ V
        #pragma unroll
        for (int dt = 0; dt < 4; ++dt) {
            #pragma unroll
            for (int kk = 0; kk < 2; ++kk) {
                const int row = dt * 16 + l15;
                int byte = row * 128 + (kk * 32 + lg * 8) * 2;
                byte ^= (row & 7) << 4;
                const s16x8 vf = *(const s16x8*)((const char*)Vl + byte);
                oacc[dt] = __builtin_amdgcn_mfma_f32_16x16x32_bf16(pf[kk], vf, oacc[dt], 0, 0, 0);
            }
        }
    }

    // epilogue: O[b][i][h*64+d]
    float inv[4];
    #pragma unroll
    for (int r = 0; r < 4; ++r) inv[r] = 1.0f / l_run[r];
    #pragma unroll
    for (int dt = 0; dt < 4; ++dt)
        #pragma unroll
        for (int r = 0; r < 4; ++r) {
            const int i = q0 + wid * 16 + lg * 4 + r;
            const int d = dt * 16 + l15;
            O[((size_t)(b * 2048 + i)) * 1024 + h * 64 + d] = f2bf(oacc[dt][r] * inv[r]);
        }
}

// ---------- launcher ----------
extern "C" void kernel_launch(void* const* d_in, const int* in_sizes, int n_in,
                              void* d_out, int out_size, void* d_ws, size_t ws_size,
                              hipStream_t stream) {
    (void)in_sizes; (void)n_in; (void)out_size; (void)ws_size;
    const float* x   = (const float*)d_in[0];
    const float* lnw = (const float*)d_in[1];
    const float* lnb = (const float*)d_in[2];
    const float* Wq  = (const float*)d_in[3];
    const float* Wk  = (const float*)d_in[4];
    const float* Wv  = (const float*)d_in[5];
    const float* Wo  = (const float*)d_in[6];
    // d_in[7] = M (ALiBi) — computed analytically in-kernel, never read.

    char* w = (char*)d_ws;
    ushort* xn  = (ushort*)(w);                        // 16 MB (reused as attn output)
    ushort* wqt = (ushort*)(w + (16u << 20));          //  2 MB
    ushort* wkt = (ushort*)(w + (18u << 20));
    ushort* wvt = (ushort*)(w + (20u << 20));
    ushort* wot = (ushort*)(w + (22u << 20));
    ushort* Qb  = (ushort*)(w + (24u << 20));          // 16 MB
    ushort* Kb  = (ushort*)(w + (40u << 20));          // 16 MB
    ushort* Vtb = (ushort*)(w + (56u << 20));          // 16 MB  (total 72 MB)

    wprep_kernel<<<dim3(32, 32), 256, 0, stream>>>(Wq, wqt);
    wprep_kernel<<<dim3(32, 32), 256, 0, stream>>>(Wk, wkt);
    wprep_kernel<<<dim3(32, 32), 256, 0, stream>>>(Wv, wvt);
    wprep_kernel<<<dim3(32, 32), 256, 0, stream>>>(Wo, wot);
    ln_kernel<<<dim3(8192), 256, 0, stream>>>(x, lnw, lnb, xn);

    gemm_kernel<<<dim3(8, 64), 256, 0, stream>>>(xn, wqt, Qb, 0);
    gemm_kernel<<<dim3(8, 64), 256, 0, stream>>>(xn, wkt, Kb, 0);
    gemm_kernel<<<dim3(8, 64), 256, 0, stream>>>(xn, wvt, Vtb, 2);

    attn_kernel<<<dim3(32, 64), 256, 0, stream>>>(Qb, Kb, Vtb, xn);

    gemm_kernel<<<dim3(8, 64), 256, 0, stream>>>(xn, wot, d_out, 3);
}

// Round 2
// 408.690 us; speedup vs baseline: 1.4617x; 1.4617x over previous
//
#include <hip/hip_runtime.h>

// ---------- types / helpers ----------
using s16x8  = __attribute__((ext_vector_type(8)))  short;
using s16x4  = __attribute__((ext_vector_type(4)))  short;
using f32x4  = __attribute__((ext_vector_type(4)))  float;
using f32x16 = __attribute__((ext_vector_type(16))) float;
using u32 = unsigned int;

#define LOG2E  1.4426950408889634f
#define QSCALE 0.18033688011112042f   /* 0.125 * LOG2E folded into Q */

static __device__ __forceinline__ ushort f2bf(float f) {
    union { float f; unsigned u; } c; c.f = f;
    unsigned u = c.u;
    unsigned r = (u + 0x7fffu + ((u >> 16) & 1u)) >> 16;   // RNE
    return (ushort)r;
}

static __device__ __forceinline__ u32 cvt_pk_bf16(float a, float b) {
    u32 r;
    asm("v_cvt_pk_bf16_f32 %0, %1, %2" : "=v"(r) : "v"(a), "v"(b));
    return r;
}
static __device__ __forceinline__ void permlane32_swap(u32& a, u32& b) {
    asm volatile("v_permlane32_swap_b32 %0, %1" : "+v"(a), "+v"(b));
}
static __device__ __forceinline__ f32x16 mfma32(s16x8 a, s16x8 b, f32x16 c) {
    return __builtin_amdgcn_mfma_f32_32x32x16_bf16(a, b, c, 0, 0, 0);
}

// build PV B-fragment (8 bf16, keys hi*8..+7) from 8 in-lane P values
#define PACKFRAG(p, base, out) {                              \
    u32 a0 = cvt_pk_bf16(p[base+0], p[base+1]);               \
    u32 b0 = cvt_pk_bf16(p[base+4], p[base+5]);               \
    permlane32_swap(a0, b0);                                  \
    u32 a1 = cvt_pk_bf16(p[base+2], p[base+3]);               \
    u32 b1 = cvt_pk_bf16(p[base+6], p[base+7]);               \
    permlane32_swap(a1, b1);                                  \
    union { u32 u[4]; s16x8 v; } f_;                          \
    f_.u[0] = a0; f_.u[1] = a1; f_.u[2] = b0; f_.u[3] = b1;   \
    out = f_.v; }

// ---------- weight prep: W[k][n] f32 -> Wt[n][k] bf16 ----------
__global__ __launch_bounds__(256) void wprep_kernel(const float* __restrict__ W,
                                                    ushort* __restrict__ Wt) {
    __shared__ float tile[32][33];
    const int k0 = blockIdx.x * 32, n0 = blockIdx.y * 32;
    const int tx = threadIdx.x & 31, ty = threadIdx.x >> 5;
    #pragma unroll
    for (int i = 0; i < 32; i += 8)
        tile[ty + i][tx] = W[(size_t)(k0 + ty + i) * 1024 + n0 + tx];
    __syncthreads();
    #pragma unroll
    for (int i = 0; i < 32; i += 8)
        Wt[(size_t)(n0 + ty + i) * 1024 + k0 + tx] = f2bf(tile[tx][ty + i]);
}

// ---------- LayerNorm ----------
__global__ __launch_bounds__(256) void ln_kernel(const float* __restrict__ x,
                                                 const float* __restrict__ w,
                                                 const float* __restrict__ b,
                                                 ushort* __restrict__ xn) {
    const int row = blockIdx.x;
    const float4 v = ((const float4*)(x + (size_t)row * 1024))[threadIdx.x];
    float s  = v.x + v.y + v.z + v.w;
    float s2 = v.x * v.x + v.y * v.y + v.z * v.z + v.w * v.w;
    #pragma unroll
    for (int off = 1; off < 64; off <<= 1) {
        s  += __shfl_xor(s, off);
        s2 += __shfl_xor(s2, off);
    }
    __shared__ float red[8];
    const int wid = threadIdx.x >> 6, lane = threadIdx.x & 63;
    if (lane == 0) { red[wid] = s; red[4 + wid] = s2; }
    __syncthreads();
    s  = red[0] + red[1] + red[2] + red[3];
    s2 = red[4] + red[5] + red[6] + red[7];
    const float mu = s * (1.0f / 1024.0f);
    const float var = s2 * (1.0f / 1024.0f) - mu * mu;
    const float rstd = rsqrtf(var + 1e-5f);
    const float4 wv = ((const float4*)w)[threadIdx.x];
    const float4 bv = ((const float4*)b)[threadIdx.x];
    s16x4 o;
    o[0] = (short)f2bf((v.x - mu) * rstd * wv.x + bv.x);
    o[1] = (short)f2bf((v.y - mu) * rstd * wv.y + bv.y);
    o[2] = (short)f2bf((v.z - mu) * rstd * wv.z + bv.z);
    o[3] = (short)f2bf((v.w - mu) * rstd * wv.w + bv.w);
    ((s16x4*)xn)[(size_t)row * 256 + threadIdx.x] = o;
}

// ---------- GEMM: C[8192,1024] = A @ W  (Wt[n][k] bf16) ----------
// mode 0: bf16 head-major [b,h,i,d] * oscale   (Q scaled, K unit)
// mode 2: bf16 head-transposed [b,h,d,i]        (V)
// mode 3: f32 plain [row][col]                  (final output)
__global__ __launch_bounds__(256) void gemm_kernel(const ushort* __restrict__ A,
                                                   const ushort* __restrict__ Wt,
                                                   void* __restrict__ outp, int mode,
                                                   float oscale) {
    const int wid = threadIdx.x >> 6;
    const int lane = threadIdx.x & 63;
    const int l15 = lane & 15;
    const int lg  = lane >> 4;
    const int m0 = blockIdx.y * 128 + (wid >> 1) * 64;
    const int n0 = blockIdx.x * 128 + (wid & 1) * 64;

    f32x4 acc[4][4] = {};
    for (int k0 = 0; k0 < 1024; k0 += 32) {
        const int ka = k0 + lg * 8;
        s16x8 a[4], bfr[4];
        #pragma unroll
        for (int mi = 0; mi < 4; ++mi)
            a[mi] = *(const s16x8*)(A + (size_t)(m0 + mi * 16 + l15) * 1024 + ka);
        #pragma unroll
        for (int ni = 0; ni < 4; ++ni)
            bfr[ni] = *(const s16x8*)(Wt + (size_t)(n0 + ni * 16 + l15) * 1024 + ka);
        #pragma unroll
        for (int mi = 0; mi < 4; ++mi)
            #pragma unroll
            for (int ni = 0; ni < 4; ++ni)
                acc[mi][ni] = __builtin_amdgcn_mfma_f32_16x16x32_bf16(a[mi], bfr[ni], acc[mi][ni], 0, 0, 0);
    }

    #pragma unroll
    for (int mi = 0; mi < 4; ++mi) {
        #pragma unroll
        for (int ni = 0; ni < 4; ++ni) {
            const int row = m0 + mi * 16 + lg * 4;
            const int col = n0 + ni * 16 + l15;
            if (mode == 0) {
                const int bb = row >> 11, i = row & 2047;
                const int h = col >> 6, d = col & 63;
                ushort* o = (ushort*)outp;
                const size_t base = (((size_t)(bb * 16 + h)) * 2048 + i) * 64 + d;
                #pragma unroll
                for (int r = 0; r < 4; ++r) o[base + (size_t)r * 64] = f2bf(acc[mi][ni][r] * oscale);
            } else if (mode == 2) {
                const int bb = row >> 11, i = row & 2047;
                const int h = col >> 6, d = col & 63;
                ushort* o = (ushort*)outp;
                const size_t base = (((size_t)(bb * 16 + h)) * 64 + d) * 2048 + i;
                s16x4 pk;
                #pragma unroll
                for (int r = 0; r < 4; ++r) pk[r] = (short)f2bf(acc[mi][ni][r]);
                *(s16x4*)(o + base) = pk;
            } else {
                float* o = (float*)outp;
                #pragma unroll
                for (int r = 0; r < 4; ++r) o[(size_t)(row + r) * 1024 + col] = acc[mi][ni][r];
            }
        }
    }
}

// ---------- attention: 8 warps x 32 q-rows, swapped QK^T, in-register softmax ----------
// Q (pre-scaled by 0.125*log2e), K: [bh][2048][64] bf16 ; Vt: [bh][64][2048] bf16
// O: [b][i][1024] bf16
__global__ __launch_bounds__(512) void attn_kernel(const ushort* __restrict__ Q,
                                                   const ushort* __restrict__ K,
                                                   const ushort* __restrict__ Vt,
                                                   ushort* __restrict__ O) {
    __shared__ __align__(16) char lds[32768];   // buf b @ b*16384: K[64][128B] + V[64][128B]

    // XCD clustering: 8 consecutive logical blocks (same bh) per XCD
    const int bid = blockIdx.x;
    const int logical = ((bid & 7) << 6) + (bid >> 3);
    const int bh = logical >> 3;
    const int b = bh >> 4, h = bh & 15;
    const int q0 = (logical & 7) * 256;

    const int wid = threadIdx.x >> 6, lane = threadIdx.x & 63;
    const int l31 = lane & 31, hi = lane >> 5;
    const float slope2 = exp2f(-8.0f / (float)(16 - h)) * LOG2E;

    const ushort* Qh = Q  + (size_t)bh * (2048 * 64);
    const ushort* Kh = K  + (size_t)bh * (2048 * 64);
    const ushort* Vh = Vt + (size_t)bh * (64 * 2048);

    const int qw = q0 + wid * 32;
    const int qi = qw + l31;

    // Q fragments (B-operand): col q = l31, k = c*16 + hi*8
    s16x8 qf[4];
    #pragma unroll
    for (int c = 0; c < 4; ++c)
        qf[c] = *(const s16x8*)(Qh + (size_t)qi * 64 + c * 16 + hi * 8);

    const float fq4 = (float)(qi - 4 * hi);   // Δ = fq4 - j0s - ((r&3)+8*(r>>2))

    // staging assignment: thread covers (row = tid>>3, c16 = tid&7), 16B each
    const int srow = threadIdx.x >> 3;
    const int sc16 = threadIdx.x & 7;
    const int swc  = sc16 ^ (srow & 7);                 // XOR-swizzled column
    const ushort* ksrc = Kh + (size_t)srow * 64 + sc16 * 8;
    const ushort* vsrc = Vh + (size_t)srow * 2048 + sc16 * 8;
    char* kdst = lds + srow * 128 + swc * 16;
    char* vdst = kdst + 8192;

    float m_run = -1e30f, l_run = 0.0f;
    f32x16 oacc0 = {}, oacc1 = {};

    // prologue: tile 0 -> buf 0
    {
        s16x8 k0v = *(const s16x8*)(ksrc);
        s16x8 v0v = *(const s16x8*)(vsrc);
        *(s16x8*)(kdst) = k0v;
        *(s16x8*)(vdst) = v0v;
    }
    __syncthreads();

    #pragma unroll 2
    for (int t = 0; t < 32; ++t) {
        const int cur = (t & 1) * 16384;
        const int j0 = t * 64;
        const char* Kl = lds + cur;
        const char* Vl = lds + cur + 8192;

        // T14: issue next tile's global loads early
        s16x8 stK, stV;
        if (t < 31) {
            stK = *(const s16x8*)(ksrc + (size_t)(j0 + 64) * 64);
            stV = *(const s16x8*)(vsrc + (j0 + 64));
        }

        // S^T = K·Q^T  (two 32-key subtiles)
        f32x16 sa0 = {}, sa1 = {};
        __builtin_amdgcn_s_setprio(1);
        #pragma unroll
        for (int c = 0; c < 4; ++c) {
            const int ck = (2 * c + hi) ^ (l31 & 7);
            s16x8 kf0 = *(const s16x8*)(Kl + l31 * 128 + ck * 16);
            s16x8 kf1 = *(const s16x8*)(Kl + (32 + l31) * 128 + ck * 16);
            sa0 = mfma32(kf0, qf[c], sa0);
            sa1 = mfma32(kf1, qf[c], sa1);
        }
        __builtin_amdgcn_s_setprio(0);

        // scores in log2 domain + ALiBi; row max (in-lane + cross-half)
        float t0[16], t1[16];
        const float base0 = fq4 - (float)j0;
        const float base1 = base0 - 32.0f;
        float mx = -1e30f;
        #pragma unroll
        for (int r = 0; r < 16; ++r) {
            const float C = (float)((r & 3) + 8 * (r >> 2));
            t0[r] = fmaf(-slope2, fabsf(base0 - C), sa0[r]);
            t1[r] = fmaf(-slope2, fabsf(base1 - C), sa1[r]);
            mx = fmaxf(mx, fmaxf(t0[r], t1[r]));
        }
        mx = fmaxf(mx, __shfl_xor(mx, 32));

        // T13: defer-max
        if (!__all(mx <= m_run + 8.0f)) {
            const float mnew = fmaxf(m_run, mx);
            const float sc = exp2f(m_run - mnew);
            l_run *= sc;
            oacc0 *= sc;
            oacc1 *= sc;
            m_run = mnew;
        }

        // P = exp2(t - m), partial row-sum (this lane's 32 keys)
        float ps = 0.0f;
        #pragma unroll
        for (int r = 0; r < 16; ++r) {
            t0[r] = exp2f(t0[r] - m_run);
            t1[r] = exp2f(t1[r] - m_run);
            ps += t0[r] + t1[r];
        }
        l_run += ps;

        // T12: P -> bf16 B-fragments in-register
        s16x8 pb00, pb01, pb10, pb11;
        PACKFRAG(t0, 0, pb00);  PACKFRAG(t0, 8, pb01);
        PACKFRAG(t1, 0, pb10);  PACKFRAG(t1, 8, pb11);

        // O^T += V^T · P^T
        __builtin_amdgcn_s_setprio(1);
        #pragma unroll
        for (int s = 0; s < 2; ++s) {
            #pragma unroll
            for (int kc = 0; kc < 2; ++kc) {
                const s16x8 pw = (s == 0) ? (kc == 0 ? pb00 : pb01)
                                          : (kc == 0 ? pb10 : pb11);
                const int ck = (s * 4 + kc * 2 + hi) ^ (l31 & 7);
                s16x8 vf0 = *(const s16x8*)(Vl + l31 * 128 + ck * 16);
                s16x8 vf1 = *(const s16x8*)(Vl + (32 + l31) * 128 + ck * 16);
                oacc0 = mfma32(vf0, pw, oacc0);
                oacc1 = mfma32(vf1, pw, oacc1);
            }
        }
        __builtin_amdgcn_s_setprio(0);

        // T14: late LDS write of next tile into other buffer
        if (t < 31) {
            const int nxt = cur ^ 16384;
            *(s16x8*)(kdst + nxt) = stK;
            *(s16x8*)(vdst + nxt) = stV;
        }
        __syncthreads();
    }

    // epilogue: normalize, transpose via per-warp LDS tile, coalesced store
    const float lt = l_run + __shfl_xor(l_run, 32);
    const float inv = 1.0f / lt;

    char* ep = lds + wid * 4096;   // [32 q][64 d] bf16, XOR-swizzled rows
    #pragma unroll
    for (int dt = 0; dt < 2; ++dt) {
        #pragma unroll
        for (int pr = 0; pr < 8; ++pr) {
            const float va = (dt ? oacc1[2 * pr] : oacc0[2 * pr]) * inv;
            const float vb = (dt ? oacc1[2 * pr + 1] : oacc0[2 * pr + 1]) * inv;
            const u32 w = cvt_pk_bf16(va, vb);
            const int d0 = dt * 32 + ((2 * pr) & 3) + 8 * (pr >> 1) + 4 * hi;
            const int byte = l31 * 128 + ((d0 * 2) ^ ((l31 & 7) << 4));
            *(u32*)(ep + byte) = w;
        }
    }
    #pragma unroll
    for (int rr = 0; rr < 4; ++rr) {
        const int row = (lane >> 3) + rr * 8;
        const int c16 = (lane & 7) ^ (row & 7);
        const s16x8 v = *(const s16x8*)(ep + row * 128 + c16 * 16);
        *(s16x8*)(O + ((size_t)(b * 2048 + qw + row)) * 1024 + h * 64 + (lane & 7) * 8) = v;
    }
}

// ---------- launcher ----------
extern "C" void kernel_launch(void* const* d_in, const int* in_sizes, int n_in,
                              void* d_out, int out_size, void* d_ws, size_t ws_size,
                              hipStream_t stream) {
    (void)in_sizes; (void)n_in; (void)out_size; (void)ws_size;
    const float* x   = (const float*)d_in[0];
    const float* lnw = (const float*)d_in[1];
    const float* lnb = (const float*)d_in[2];
    const float* Wq  = (const float*)d_in[3];
    const float* Wk  = (const float*)d_in[4];
    const float* Wv  = (const float*)d_in[5];
    const float* Wo  = (const float*)d_in[6];
    // d_in[7] = M (ALiBi) — computed analytically in-kernel, never read.

    char* w = (char*)d_ws;
    ushort* xn  = (ushort*)(w);                        // 16 MB (reused as attn output)
    ushort* wqt = (ushort*)(w + (16u << 20));          //  2 MB each
    ushort* wkt = (ushort*)(w + (18u << 20));
    ushort* wvt = (ushort*)(w + (20u << 20));
    ushort* wot = (ushort*)(w + (22u << 20));
    ushort* Qb  = (ushort*)(w + (24u << 20));          // 16 MB
    ushort* Kb  = (ushort*)(w + (40u << 20));          // 16 MB
    ushort* Vtb = (ushort*)(w + (56u << 20));          // 16 MB

    wprep_kernel<<<dim3(32, 32), 256, 0, stream>>>(Wq, wqt);
    wprep_kernel<<<dim3(32, 32), 256, 0, stream>>>(Wk, wkt);
    wprep_kernel<<<dim3(32, 32), 256, 0, stream>>>(Wv, wvt);
    wprep_kernel<<<dim3(32, 32), 256, 0, stream>>>(Wo, wot);
    ln_kernel<<<dim3(8192), 256, 0, stream>>>(x, lnw, lnb, xn);

    gemm_kernel<<<dim3(8, 64), 256, 0, stream>>>(xn, wqt, Qb, 0, QSCALE);
    gemm_kernel<<<dim3(8, 64), 256, 0, stream>>>(xn, wkt, Kb, 0, 1.0f);
    gemm_kernel<<<dim3(8, 64), 256, 0, stream>>>(xn, wvt, Vtb, 2, 1.0f);

    attn_kernel<<<dim3(512), 512, 0, stream>>>(Qb, Kb, Vtb, xn);

    gemm_kernel<<<dim3(8, 64), 256, 0, stream>>>(xn, wot, d_out, 3, 1.0f);
}

// Round 4
// 268.653 us; speedup vs baseline: 2.2237x; 1.5213x over previous
//
#include <hip/hip_runtime.h>

// ---------- types / helpers ----------
using s16x8  = __attribute__((ext_vector_type(8)))  short;
using s16x4  = __attribute__((ext_vector_type(4)))  short;
using f32x4  = __attribute__((ext_vector_type(4)))  float;
using f32x16 = __attribute__((ext_vector_type(16))) float;
using u32 = unsigned int;

#define LOG2E  1.4426950408889634f
#define QSCALE 0.18033688011112042f   /* 0.125 * LOG2E folded into Wq */

static __device__ __forceinline__ ushort f2bf(float f) {
    union { float f; unsigned u; } c; c.f = f;
    unsigned u = c.u;
    unsigned r = (u + 0x7fffu + ((u >> 16) & 1u)) >> 16;   // RNE
    return (ushort)r;
}
static __device__ __forceinline__ float bf2f(ushort h) {
    union { unsigned u; float f; } c; c.u = ((unsigned)h) << 16;
    return c.f;
}
static __device__ __forceinline__ u32 cvt_pk_bf16(float a, float b) {
    u32 r;
    asm("v_cvt_pk_bf16_f32 %0, %1, %2" : "=v"(r) : "v"(a), "v"(b));
    return r;
}
static __device__ __forceinline__ void permlane32_swap(u32& a, u32& b) {
    asm volatile("v_permlane32_swap_b32 %0, %1" : "+v"(a), "+v"(b));
}
static __device__ __forceinline__ f32x16 mfma32(s16x8 a, s16x8 b, f32x16 c) {
    return __builtin_amdgcn_mfma_f32_32x32x16_bf16(a, b, c, 0, 0, 0);
}
// async global->LDS, 16B per lane; lds ptr must be wave-uniform
typedef __attribute__((address_space(3))) void lds_vt;
typedef __attribute__((address_space(1))) const void glb_vt;
static __device__ __forceinline__ void gload16(const void* g, void* l) {
    __builtin_amdgcn_global_load_lds((glb_vt*)g, (lds_vt*)l, 16, 0, 0);
}

// build PV B-fragment (8 bf16, keys hi*8..+7) from 8 in-lane P values
#define PACKFRAG(p, base, out) {                              \
    u32 a0 = cvt_pk_bf16(p[base+0], p[base+1]);               \
    u32 b0 = cvt_pk_bf16(p[base+4], p[base+5]);               \
    permlane32_swap(a0, b0);                                  \
    u32 a1 = cvt_pk_bf16(p[base+2], p[base+3]);               \
    u32 b1 = cvt_pk_bf16(p[base+6], p[base+7]);               \
    permlane32_swap(a1, b1);                                  \
    union { u32 u[4]; s16x8 v; } f_;                          \
    f_.u[0] = a0; f_.u[1] = a1; f_.u[2] = b0; f_.u[3] = b1;   \
    out = f_.v; }

// ---------- weight prep: W[k][n] f32 -> Wt[n][k] bf16 (* scale) ----------
__global__ __launch_bounds__(256) void wprep_kernel(const float* __restrict__ W,
                                                    ushort* __restrict__ Wt, float scale) {
    __shared__ float tile[32][33];
    const int k0 = blockIdx.x * 32, n0 = blockIdx.y * 32;
    const int tx = threadIdx.x & 31, ty = threadIdx.x >> 5;
    #pragma unroll
    for (int i = 0; i < 32; i += 8)
        tile[ty + i][tx] = W[(size_t)(k0 + ty + i) * 1024 + n0 + tx];
    __syncthreads();
    #pragma unroll
    for (int i = 0; i < 32; i += 8)
        Wt[(size_t)(n0 + ty + i) * 1024 + k0 + tx] = f2bf(tile[tx][ty + i] * scale);
}

// ---------- LayerNorm ----------
__global__ __launch_bounds__(256) void ln_kernel(const float* __restrict__ x,
                                                 const float* __restrict__ w,
                                                 const float* __restrict__ b,
                                                 ushort* __restrict__ xn) {
    const int row = blockIdx.x;
    const float4 v = ((const float4*)(x + (size_t)row * 1024))[threadIdx.x];
    float s  = v.x + v.y + v.z + v.w;
    float s2 = v.x * v.x + v.y * v.y + v.z * v.z + v.w * v.w;
    #pragma unroll
    for (int off = 1; off < 64; off <<= 1) {
        s  += __shfl_xor(s, off);
        s2 += __shfl_xor(s2, off);
    }
    __shared__ float red[8];
    const int wid = threadIdx.x >> 6, lane = threadIdx.x & 63;
    if (lane == 0) { red[wid] = s; red[4 + wid] = s2; }
    __syncthreads();
    s  = red[0] + red[1] + red[2] + red[3];
    s2 = red[4] + red[5] + red[6] + red[7];
    const float mu = s * (1.0f / 1024.0f);
    const float var = s2 * (1.0f / 1024.0f) - mu * mu;
    const float rstd = rsqrtf(var + 1e-5f);
    const float4 wv = ((const float4*)w)[threadIdx.x];
    const float4 bv = ((const float4*)b)[threadIdx.x];
    s16x4 o;
    o[0] = (short)f2bf((v.x - mu) * rstd * wv.x + bv.x);
    o[1] = (short)f2bf((v.y - mu) * rstd * wv.y + bv.y);
    o[2] = (short)f2bf((v.z - mu) * rstd * wv.z + bv.z);
    o[3] = (short)f2bf((v.w - mu) * rstd * wv.w + bv.w);
    ((s16x4*)xn)[(size_t)row * 256 + threadIdx.x] = o;
}

// ---------- GEMM (m97 structure): C[8192,N] = A[8192,1024] x Wt[N,1024]^T ----------
// omode 0: N=3072 fused QKV -> Q/K head-major bf16, V head-transposed bf16
// omode 1: N=1024 -> f32 [row][col]
__global__ __launch_bounds__(256) void gemm_kernel(const ushort* __restrict__ A,
                                                   const ushort* __restrict__ Wt,
                                                   ushort* __restrict__ oq,
                                                   float* __restrict__ of,
                                                   int nblkn, int omode) {
    __shared__ ushort As[128 * 32];
    __shared__ ushort Bs[128 * 32];

    const int nwg = gridDim.x;
    const int cpx = nwg >> 3;
    const int bid = blockIdx.x;
    const int logical = (bid & 7) * cpx + (bid >> 3);   // XCD cluster (nwg % 8 == 0)
    const int mb = logical / nblkn, nb = logical % nblkn;
    const int m0 = mb * 128, n0 = nb * 128;

    const int wid = threadIdx.x >> 6, lane = threadIdx.x & 63;
    const int l15 = lane & 15, lg = lane >> 4;
    const int wm = (wid >> 1) * 64, wn = (wid & 1) * 64;

    const int trow = threadIdx.x >> 2;                  // 0..63
    const int tchk = threadIdx.x & 3;
    const ushort* ga0 = A  + (size_t)(m0 + trow) * 1024 + tchk * 8;
    const ushort* ga1 = ga0 + 64 * 1024;
    const ushort* gb0 = Wt + (size_t)(n0 + trow) * 1024 + tchk * 8;
    const ushort* gb1 = gb0 + 64 * 1024;
    ushort* lA = As + wid * 512;                        // wave-uniform LDS bases
    ushort* lB = Bs + wid * 512;

    f32x4 acc[4][4] = {};
    for (int k0 = 0; k0 < 1024; k0 += 32) {
        __syncthreads();
        gload16(ga0 + k0, lA);
        gload16(ga1 + k0, lA + 2048);
        gload16(gb0 + k0, lB);
        gload16(gb1 + k0, lB + 2048);
        __syncthreads();
        s16x8 af[4], bf[4];
        #pragma unroll
        for (int mi = 0; mi < 4; ++mi)
            af[mi] = *(const s16x8*)(As + (wm + mi * 16 + l15) * 32 + lg * 8);
        #pragma unroll
        for (int ni = 0; ni < 4; ++ni)
            bf[ni] = *(const s16x8*)(Bs + (wn + ni * 16 + l15) * 32 + lg * 8);
        #pragma unroll
        for (int mi = 0; mi < 4; ++mi)
            #pragma unroll
            for (int ni = 0; ni < 4; ++ni)
                acc[mi][ni] = __builtin_amdgcn_mfma_f32_16x16x32_bf16(af[mi], bf[ni], acc[mi][ni], 0, 0, 0);
    }

    #pragma unroll
    for (int mi = 0; mi < 4; ++mi) {
        #pragma unroll
        for (int ni = 0; ni < 4; ++ni) {
            const int row = m0 + wm + mi * 16 + lg * 4;
            const int col = n0 + wn + ni * 16 + l15;
            if (omode == 0) {
                const int t = col >> 10;
                const int h = (col >> 6) & 15, d = col & 63;
                const int bb = row >> 11, i = row & 2047;
                if (t < 2) {       // Q or K: [bh][i][d]
                    ushort* o = oq + ((size_t)t << 23) + ((((size_t)(bb * 16 + h)) * 2048 + i) * 64 + d);
                    #pragma unroll
                    for (int r = 0; r < 4; ++r) o[(size_t)r * 64] = f2bf(acc[mi][ni][r]);
                } else {           // V: [bh][d][i]
                    ushort* o = oq + ((size_t)2 << 23) + ((((size_t)(bb * 16 + h)) * 64 + d) * 2048 + i);
                    s16x4 pk;
                    #pragma unroll
                    for (int r = 0; r < 4; ++r) pk[r] = (short)f2bf(acc[mi][ni][r]);
                    *(s16x4*)o = pk;
                }
            } else {
                #pragma unroll
                for (int r = 0; r < 4; ++r) of[(size_t)(row + r) * 1024 + col] = acc[mi][ni][r];
            }
        }
    }
}

// ---------- attention: 4 warps x 32 q-rows, ALiBi-in-MFMA, m=0 softmax ----------
// Q (pre-scaled), K: [bh][2048][64] bf16 ; Vt: [bh][64][2048] bf16 ; O: [b][i][1024] bf16
#define KSTR 160           /* padded LDS row stride (bytes) for 128B rows */
#define BUFSZ 20480        /* K tile 64*160 + V tile 64*160 */
__global__ __launch_bounds__(256) void attn_kernel(const ushort* __restrict__ Q,
                                                   const ushort* __restrict__ K,
                                                   const ushort* __restrict__ Vt,
                                                   ushort* __restrict__ O) {
    __shared__ __align__(16) char lds[2 * BUFSZ];

    const int bid = blockIdx.x;
    const int logical = (bid & 7) * 128 + (bid >> 3);   // 1024 blocks, XCD-clustered
    const int bh = logical >> 4;
    const int b = bh >> 4, h = bh & 15;
    const int q0 = (logical & 15) * 128;

    const int wid = threadIdx.x >> 6, lane = threadIdx.x & 63;
    const int l31 = lane & 31, hi = lane >> 5;
    const float slope2 = exp2f(-8.0f / (float)(16 - h)) * LOG2E;

    const ushort* Qh = Q  + (size_t)bh * (2048 * 64);
    const ushort* Kh = K  + (size_t)bh * (2048 * 64);
    const ushort* Vh = Vt + (size_t)bh * (64 * 2048);

    const int qw = q0 + wid * 32;
    const int qi = qw + l31;
    const float qif = (float)qi;
    const float fq4 = (float)(qi - 4 * hi);

    s16x8 qf[4];
    #pragma unroll
    for (int c = 0; c < 4; ++c)
        qf[c] = *(const s16x8*)(Qh + (size_t)qi * 64 + c * 16 + hi * 8);

    // --- ALiBi extension fragments (K side, constant) ---
    const u32 hmask = hi ? 0u : 0xFFFFFFFFu;
    union { u32 u[4]; s16x8 v; } kxa, kxb, onf;
    kxa.u[0] = cvt_pk_bf16((float)l31 - 32.f, (float)l31 - 32.f) & hmask;
    kxa.u[1] = 0x3F803F80u & hmask; kxa.u[2] = 0; kxa.u[3] = 0;
    kxb.u[0] = cvt_pk_bf16((float)l31, (float)l31) & hmask;
    kxb.u[1] = kxa.u[1]; kxb.u[2] = 0; kxb.u[3] = 0;
    const u32 onesu = (l31 == 0) ? 0x3F803F80u : 0u;   // row-0 ones (row-sum via MFMA)
    onf.u[0] = onesu; onf.u[1] = onesu; onf.u[2] = onesu; onf.u[3] = onesu;
    // slope2 hi/lo split (Q side), both signs
    const float s2h = bf2f(f2bf(slope2));
    const float s2l = slope2 - s2h;
    const u32 wpos = ((u32)f2bf(s2l) << 16) | (u32)f2bf(s2h);
    const u32 wneg = wpos ^ 0x80008000u;

    // staging: 2 iters x 256 threads cover 64 rows x 8 chunks (16B)
    const ushort* ksrc[2]; const ushort* vsrc[2]; char* kdst[2]; char* vdst[2];
    #pragma unroll
    for (int it = 0; it < 2; ++it) {
        const int idx = threadIdx.x + it * 256;
        const int srow = idx >> 3, sc = idx & 7;
        const int swc = sc ^ (srow & 7);
        ksrc[it] = Kh + (size_t)srow * 64 + sc * 8;
        vsrc[it] = Vh + (size_t)srow * 2048 + sc * 8;
        kdst[it] = lds + srow * KSTR + swc * 16;
        vdst[it] = kdst[it] + 64 * KSTR;
    }

    f32x16 oacc0 = {}, oacc1 = {}, lacc = {};

    #pragma unroll
    for (int it = 0; it < 2; ++it) {
        *(s16x8*)(kdst[it]) = *(const s16x8*)(ksrc[it]);
        *(s16x8*)(vdst[it]) = *(const s16x8*)(vsrc[it]);
    }
    __syncthreads();

    #pragma unroll 2
    for (int t = 0; t < 32; ++t) {
        const int cur = (t & 1) * BUFSZ;
        const int j0 = t * 64;
        const char* Kl = lds + cur;
        const char* Vl = lds + cur + 64 * KSTR;

        s16x8 stK[2], stV[2];
        if (t < 31) {
            #pragma unroll
            for (int it = 0; it < 2; ++it) {
                stK[it] = *(const s16x8*)(ksrc[it] + (size_t)(j0 + 64) * 64);
                stV[it] = *(const s16x8*)(vsrc[it] + (j0 + 64));
            }
        }

        // S^T = K·Q^T
        f32x16 sa0 = {}, sa1 = {};
        __builtin_amdgcn_s_setprio(1);
        #pragma unroll
        for (int c = 0; c < 4; ++c) {
            const int ck = (2 * c + hi) ^ (l31 & 7);
            s16x8 kf0 = *(const s16x8*)(Kl + l31 * KSTR + ck * 16);
            s16x8 kf1 = *(const s16x8*)(Kl + (32 + l31) * KSTR + ck * 16);
            sa0 = mfma32(kf0, qf[c], sa0);
            sa1 = mfma32(kf1, qf[c], sa1);
        }
        __builtin_amdgcn_s_setprio(0);

        const bool strad = (j0 > qw - 64) && (j0 < qw + 32);
        if (!strad) {
            // rank-2 ALiBi via one extra MFMA per 32-key half
            const bool left = (j0 <= qw - 64);          // all keys left: s=+1
            const float v = (left ? -slope2 : slope2) * (qif - (float)(j0 + 32));
            const u32 pk0 = cvt_pk_bf16(v, 0.f);
            union { u32 u; float f; } vh; vh.u = pk0 << 16;
            const u32 w1 = cvt_pk_bf16(vh.f, v - vh.f) & hmask;
            union { u32 u[4]; s16x8 v8; } qx;
            qx.u[0] = (left ? wpos : wneg) & hmask;
            qx.u[1] = w1; qx.u[2] = 0; qx.u[3] = 0;
            sa0 = mfma32(kxa.v, qx.v8, sa0);
            sa1 = mfma32(kxb.v, qx.v8, sa1);
            #pragma unroll
            for (int r = 0; r < 16; ++r) {
                sa0[r] = __builtin_amdgcn_exp2f(sa0[r]);
                sa1[r] = __builtin_amdgcn_exp2f(sa1[r]);
            }
        } else {
            const float base0 = fq4 - (float)j0;
            #pragma unroll
            for (int r = 0; r < 16; ++r) {
                const float C = (float)((r & 3) + 8 * (r >> 2));
                sa0[r] = __builtin_amdgcn_exp2f(fmaf(-slope2, fabsf(base0 - C), sa0[r]));
                sa1[r] = __builtin_amdgcn_exp2f(fmaf(-slope2, fabsf(base0 - 32.0f - C), sa1[r]));
            }
        }

        // P -> bf16 B-fragments in-register
        s16x8 pb00, pb01, pb10, pb11;
        PACKFRAG(sa0, 0, pb00);  PACKFRAG(sa0, 8, pb01);
        PACKFRAG(sa1, 0, pb10);  PACKFRAG(sa1, 8, pb11);

        __builtin_amdgcn_s_setprio(1);
        // row-sum via ones-row MFMA (lands in lacc[0] on hi=0 lanes)
        lacc = mfma32(onf.v, pb00, lacc);
        lacc = mfma32(onf.v, pb01, lacc);
        lacc = mfma32(onf.v, pb10, lacc);
        lacc = mfma32(onf.v, pb11, lacc);
        // O^T += V^T · P^T
        #pragma unroll
        for (int s = 0; s < 2; ++s) {
            #pragma unroll
            for (int kc = 0; kc < 2; ++kc) {
                const s16x8 pw = (s == 0) ? (kc == 0 ? pb00 : pb01)
                                          : (kc == 0 ? pb10 : pb11);
                const int ck = (s * 4 + kc * 2 + hi) ^ (l31 & 7);
                s16x8 vf0 = *(const s16x8*)(Vl + l31 * KSTR + ck * 16);
                s16x8 vf1 = *(const s16x8*)(Vl + (32 + l31) * KSTR + ck * 16);
                oacc0 = mfma32(vf0, pw, oacc0);
                oacc1 = mfma32(vf1, pw, oacc1);
            }
        }
        __builtin_amdgcn_s_setprio(0);

        if (t < 31) {
            const int nxt = cur ^ BUFSZ;
            #pragma unroll
            for (int it = 0; it < 2; ++it) {
                *(s16x8*)(kdst[it] + nxt) = stK[it];
                *(s16x8*)(vdst[it] + nxt) = stV[it];
            }
        }
        __syncthreads();
    }

    // epilogue: normalize, transpose via per-warp LDS tile, coalesced store
    const float lt = lacc[0] + __shfl_xor(lacc[0], 32);
    const float inv = 1.0f / lt;

    char* ep = lds + wid * 4096;   // [32 q][64 d] bf16, XOR-swizzled rows
    #pragma unroll
    for (int dt = 0; dt < 2; ++dt) {
        #pragma unroll
        for (int pr = 0; pr < 8; ++pr) {
            const float va = (dt ? oacc1[2 * pr] : oacc0[2 * pr]) * inv;
            const float vb = (dt ? oacc1[2 * pr + 1] : oacc0[2 * pr + 1]) * inv;
            const u32 w = cvt_pk_bf16(va, vb);
            const int d0 = dt * 32 + ((2 * pr) & 3) + 8 * (pr >> 1) + 4 * hi;
            const int byte = l31 * 128 + ((d0 * 2) ^ ((l31 & 7) << 4));
            *(u32*)(ep + byte) = w;
        }
    }
    #pragma unroll
    for (int rr = 0; rr < 4; ++rr) {
        const int row = (lane >> 3) + rr * 8;
        const int c16 = (lane & 7) ^ (row & 7);
        const s16x8 v = *(const s16x8*)(ep + row * 128 + c16 * 16);
        *(s16x8*)(O + ((size_t)(b * 2048 + qw + row)) * 1024 + h * 64 + (lane & 7) * 8) = v;
    }
}

// ---------- launcher ----------
extern "C" void kernel_launch(void* const* d_in, const int* in_sizes, int n_in,
                              void* d_out, int out_size, void* d_ws, size_t ws_size,
                              hipStream_t stream) {
    (void)in_sizes; (void)n_in; (void)out_size; (void)ws_size;
    const float* x   = (const float*)d_in[0];
    const float* lnw = (const float*)d_in[1];
    const float* lnb = (const float*)d_in[2];
    const float* Wq  = (const float*)d_in[3];
    const float* Wk  = (const float*)d_in[4];
    const float* Wv  = (const float*)d_in[5];
    const float* Wo  = (const float*)d_in[6];
    // d_in[7] = M (ALiBi) — computed analytically in-kernel, never read.

    char* w = (char*)d_ws;
    ushort* xn   = (ushort*)(w);                       // 16 MB (attn output reuses)
    ushort* wqkv = (ushort*)(w + (16u << 20));         //  6 MB: [3072][1024]
    ushort* wot  = (ushort*)(w + (22u << 20));         //  2 MB
    ushort* Qb   = (ushort*)(w + (24u << 20));         // 48 MB: Q | K | Vt

    wprep_kernel<<<dim3(32, 32), 256, 0, stream>>>(Wq, wqkv,               QSCALE);
    wprep_kernel<<<dim3(32, 32), 256, 0, stream>>>(Wk, wqkv + (1u << 20),  1.0f);
    wprep_kernel<<<dim3(32, 32), 256, 0, stream>>>(Wv, wqkv + (2u << 20),  1.0f);
    wprep_kernel<<<dim3(32, 32), 256, 0, stream>>>(Wo, wot,                1.0f);
    ln_kernel<<<dim3(8192), 256, 0, stream>>>(x, lnw, lnb, xn);

    gemm_kernel<<<dim3(1536), 256, 0, stream>>>(xn, wqkv, Qb, nullptr, 24, 0);

    attn_kernel<<<dim3(1024), 256, 0, stream>>>(Qb, Qb + (1u << 23), Qb + (2u << 23), xn);

    gemm_kernel<<<dim3(512), 256, 0, stream>>>(xn, wot, nullptr, (float*)d_out, 8, 1);
}